// Round 11
// baseline (183.766 us; speedup 1.0000x reference)
//
#include <hip/hip_runtime.h>
#include <math.h>

// ---------------------------------------------------------------------------
// PointSampler / DevConv: CSR-gather (4 nodes/wave, clamp-padded, swizzle
// broadcast) fused with the next layer's MFMA fp16 GEMM. fp16-only state.
//   prep: weights->fp16 (incl. folded C2,C3,v), zero bcnt/gcur, row_ptr[N]=E
//   hist_gemm: blocks<chunkBlocks do dst-bucket histogram; rest do layer-1 GEMM
//   partA -> partB (write-coalesced CSR; each does a local scan of bcnt)
//   fused l: gather(y16) -> LDS agg tile -> MFMA -> y16other
//   final:   gather + Linear(D,1)+sigmoid head
// Gather is at the ~2 TB/s random-line L2-miss service floor (r8 vs r10:
// identical GB/ms at wildly different VALU/occupancy) — don't touch it.
// ---------------------------------------------------------------------------

#define WBITS 8
#define WNODES 256            // nodes per bucket
#define MAXNB 512             // max buckets (N <= 131072, src < 2^17)
#define CHUNK 4096            // edges per partA/hist block
#define STG_CAP 12288         // partB LDS staging entries (48 KB)

#define PKNINF 0xFC00FC00u    // packed fp16 (-inf, -inf)

typedef __fp16 h2v __attribute__((ext_vector_type(2)));
typedef _Float16 f16x8 __attribute__((ext_vector_type(8)));
typedef float f32x4 __attribute__((ext_vector_type(4)));

__device__ __forceinline__ unsigned pkmax(unsigned a, unsigned b) {
    unsigned r;
    asm("v_pk_max_f16 %0, %1, %2" : "=v"(r) : "v"(a), "v"(b));
    return r;
}
__device__ __forceinline__ unsigned pkrtz(float a, float b) {
    h2v r = __builtin_amdgcn_cvt_pkrtz(a, b);
    return *reinterpret_cast<unsigned*>(&r);
}
__device__ __forceinline__ float h2lo(unsigned u) {
    h2v h = *reinterpret_cast<h2v*>(&u);
    return (float)h.x;
}
__device__ __forceinline__ float h2hi(unsigned u) {
    h2v h = *reinterpret_cast<h2v*>(&u);
    return (float)h.y;
}

// 8 edges: broadcast col idx from quarter-lane K0+k, load 8B of fp16 row, pkmax
#define G8(K0) do { \
    int j0 = __builtin_amdgcn_ds_swizzle(myc, (((K0)+0)<<5)|0x10); \
    int j1 = __builtin_amdgcn_ds_swizzle(myc, (((K0)+1)<<5)|0x10); \
    int j2 = __builtin_amdgcn_ds_swizzle(myc, (((K0)+2)<<5)|0x10); \
    int j3 = __builtin_amdgcn_ds_swizzle(myc, (((K0)+3)<<5)|0x10); \
    int j4 = __builtin_amdgcn_ds_swizzle(myc, (((K0)+4)<<5)|0x10); \
    int j5 = __builtin_amdgcn_ds_swizzle(myc, (((K0)+5)<<5)|0x10); \
    int j6 = __builtin_amdgcn_ds_swizzle(myc, (((K0)+6)<<5)|0x10); \
    int j7 = __builtin_amdgcn_ds_swizzle(myc, (((K0)+7)<<5)|0x10); \
    uint2 w0 = y16[(size_t)j0 * 16 + t]; \
    uint2 w1 = y16[(size_t)j1 * 16 + t]; \
    uint2 w2 = y16[(size_t)j2 * 16 + t]; \
    uint2 w3 = y16[(size_t)j3 * 16 + t]; \
    uint2 w4 = y16[(size_t)j4 * 16 + t]; \
    uint2 w5 = y16[(size_t)j5 * 16 + t]; \
    uint2 w6 = y16[(size_t)j6 * 16 + t]; \
    uint2 w7 = y16[(size_t)j7 * 16 + t]; \
    c0 = pkmax(c0, pkmax(pkmax(pkmax(w0.x, w1.x), pkmax(w2.x, w3.x)), \
                         pkmax(pkmax(w4.x, w5.x), pkmax(w6.x, w7.x)))); \
    c1 = pkmax(c1, pkmax(pkmax(pkmax(w0.y, w1.y), pkmax(w2.y, w3.y)), \
                         pkmax(pkmax(w4.y, w5.y), pkmax(w6.y, w7.y)))); \
} while (0)

// block 0: Wh1 = fp16(Wp[1]@Wt[0]) + zero bcnt/gcur; block 1: Wh2 + row_ptr[N]=E;
// block 2: vv = Wout@Wt[2] (f32) and Wh0 = fp16(Wp[0])
__global__ __launch_bounds__(256) void prep_k(
    const float* __restrict__ Wp, const float* __restrict__ Wt,
    const float* __restrict__ Wout,
    __fp16* __restrict__ Wh, float* __restrict__ vout,
    int* __restrict__ bcnt, int* __restrict__ gcur,
    int* __restrict__ row_ptr, int N, int E)
{
    __shared__ float A[4096];
    __shared__ float B[4096];
    int tid = threadIdx.x;
    int b = blockIdx.x;
    if (b < 2) {
        if (b == 0) {
            for (int i = tid; i < MAXNB; i += 256) { bcnt[i] = 0; gcur[i] = 0; }
        } else if (tid == 0) {
            row_ptr[N] = E;
        }
        const float* Ap = Wp + (size_t)(b + 1) * 4096;
        const float* Bp = Wt + (size_t)b * 4096;
        for (int i = tid; i < 4096; i += 256) { A[i] = Ap[i]; B[i] = Bp[i]; }
        __syncthreads();
        __fp16* C = Wh + (size_t)(b + 1) * 4096;
        for (int i = tid; i < 4096; i += 256) {
            int d = i >> 6, k = i & 63;
            float s = 0.f;
            #pragma unroll
            for (int m = 0; m < 64; ++m) s += A[d * 64 + m] * B[m * 64 + k];
            C[i] = (__fp16)s;
        }
    } else {
        for (int i = tid; i < 4096; i += 256) {
            A[i] = Wt[2 * 4096 + i];
            Wh[i] = (__fp16)Wp[i];
        }
        if (tid < 64) B[tid] = Wout[tid];
        __syncthreads();
        if (tid < 64) {
            float s = 0.f;
            #pragma unroll
            for (int m = 0; m < 64; ++m) s += B[m] * A[m * 64 + tid];
            vout[tid] = s;
        }
    }
}

// blocks [0, chunkBlocks): per-chunk LDS histogram of dst buckets.
// blocks [chunkBlocks, ...): layer-1 MFMA GEMM  y16 = fp16(x @ Wh0.T).
__global__ __launch_bounds__(256) void hist_gemm_k(
    const int* __restrict__ eidx, int* __restrict__ bcnt, int E, int NB,
    int chunkBlocks,
    const float* __restrict__ xin, const __fp16* __restrict__ W,
    unsigned short* __restrict__ y16o, int n)
{
    __shared__ int h[MAXNB];
    int tid = threadIdx.x;
    if (blockIdx.x < chunkBlocks) {
        for (int i = tid; i < MAXNB; i += 256) h[i] = 0;
        __syncthreads();
        int start = blockIdx.x * CHUNK;
        int end = min(E, start + CHUNK);
        for (int e = start + tid; e < end; e += 256)
            atomicAdd(&h[eidx[E + e] >> WBITS], 1);
        __syncthreads();
        for (int i = tid; i < NB; i += 256)
            if (h[i]) atomicAdd(&bcnt[i], h[i]);
    } else {
        int lane = tid & 63;
        int wid  = tid >> 6;
        int r0   = ((blockIdx.x - chunkBlocks) * 4 + wid) * 16;
        if (r0 >= n) return;
        int l15 = lane & 15;
        int ko  = (lane >> 4) * 8;

        f16x8 af[4][2];
        #pragma unroll
        for (int dt = 0; dt < 4; ++dt)
            #pragma unroll
            for (int kf = 0; kf < 2; ++kf)
                af[dt][kf] = *(const f16x8*)(W + (size_t)(dt * 16 + l15) * 64 + ko + kf * 32);

        f16x8 bf[2];
        int rr = min(r0 + l15, n - 1);
        #pragma unroll
        for (int kf = 0; kf < 2; ++kf) {
            const float4* p = (const float4*)(xin + (size_t)rr * 64 + ko + kf * 32);
            float4 a = p[0], b = p[1];
            union { uint4 u; f16x8 hh; } cv;
            cv.u.x = pkrtz(a.x, a.y); cv.u.y = pkrtz(a.z, a.w);
            cv.u.z = pkrtz(b.x, b.y); cv.u.w = pkrtz(b.z, b.w);
            bf[kf] = cv.hh;
        }

        int r = r0 + l15;
        int d4 = (lane >> 4) * 4;
        #pragma unroll
        for (int dt = 0; dt < 4; ++dt) {
            f32x4 acc = {0.f, 0.f, 0.f, 0.f};
            acc = __builtin_amdgcn_mfma_f32_16x16x32_f16(af[dt][0], bf[0], acc, 0, 0, 0);
            acc = __builtin_amdgcn_mfma_f32_16x16x32_f16(af[dt][1], bf[1], acc, 0, 0, 0);
            if (r < n) {
                uint2 p; p.x = pkrtz(acc[0], acc[1]); p.y = pkrtz(acc[2], acc[3]);
                *(uint2*)(y16o + (size_t)r * 64 + dt * 16 + d4) = p;
            }
        }
    }
}

// partition edges into bucket-major order (packed src | dstLow<<17).
// Local scan of global bcnt replaces the old bucket_scan kernel; gcur is a
// zero-based offset counter (bcnt complete: kernel-boundary ordering).
__global__ __launch_bounds__(256) void partA_k(
    const int* __restrict__ eidx, const int* __restrict__ bcnt,
    int* __restrict__ gcur, int* __restrict__ B1, int E, int NB)
{
    __shared__ int hist[MAXNB];
    __shared__ int lofs[MAXNB];
    __shared__ int lcur[MAXNB];
    __shared__ int gofs[MAXNB];
    __shared__ int sA[MAXNB], sB[MAXNB];
    __shared__ int stg_val[CHUNK];
    __shared__ int stg_pos[CHUNK];
    int tid = threadIdx.x;
    int start = blockIdx.x * CHUNK;
    int cnt = min(E - start, CHUNK);
    if (cnt <= 0) return;

    for (int i = tid; i < MAXNB; i += 256) hist[i] = 0;
    __syncthreads();

    int es[CHUNK / 256], ed[CHUNK / 256];
    #pragma unroll
    for (int i = 0; i < CHUNK / 256; ++i) {
        int li = i * 256 + tid;
        if (li < cnt) {
            es[i] = eidx[start + li];
            ed[i] = eidx[E + start + li];
            atomicAdd(&hist[ed[i] >> WBITS], 1);
        }
    }
    __syncthreads();
    // scan 1: global bcnt -> exclusive bases (redundant per block, cheap)
    for (int i = tid; i < MAXNB; i += 256) sA[i] = (i < NB) ? bcnt[i] : 0;
    __syncthreads();
    int* sp = sA; int* dp = sB;
    for (int off = 1; off < MAXNB; off <<= 1) {
        for (int i = tid; i < MAXNB; i += 256)
            dp[i] = sp[i] + ((i >= off) ? sp[i - off] : 0);
        __syncthreads();
        int* t = sp; sp = dp; dp = t;
    }
    for (int i = tid; i < MAXNB; i += 256)
        gofs[i] = sp[i] - ((i < NB) ? bcnt[i] : 0);   // exclusive global base
    __syncthreads();
    // scan 2: local chunk hist -> local staging offsets
    for (int i = tid; i < MAXNB; i += 256) sp[i] = hist[i];
    __syncthreads();
    for (int off = 1; off < MAXNB; off <<= 1) {
        for (int i = tid; i < MAXNB; i += 256)
            dp[i] = sp[i] + ((i >= off) ? sp[i - off] : 0);
        __syncthreads();
        int* t = sp; sp = dp; dp = t;
    }
    for (int i = tid; i < MAXNB; i += 256) {
        int c  = hist[i];
        int ex = sp[i] - c;
        lofs[i] = ex;
        lcur[i] = ex;
        if (c) gofs[i] += atomicAdd(&gcur[i], c);
    }
    __syncthreads();
    #pragma unroll
    for (int i = 0; i < CHUNK / 256; ++i) {
        int li = i * 256 + tid;
        if (li < cnt) {
            int b = ed[i] >> WBITS;
            int p = atomicAdd(&lcur[b], 1);
            stg_val[p] = es[i] | ((ed[i] & (WNODES - 1)) << 17);
            stg_pos[p] = gofs[b] + (p - lofs[b]);
        }
    }
    __syncthreads();
    for (int i = tid; i < cnt; i += 256)
        B1[stg_pos[i]] = stg_val[i];
}

// per-bucket: degree count -> scan -> row_ptr; LDS-staged coalesced col scatter.
// Bucket bases re-derived by a local scan of bcnt.
__global__ __launch_bounds__(256) void partB_k(
    const int* __restrict__ B1, const int* __restrict__ bcnt,
    int* __restrict__ row_ptr, int* __restrict__ col, int N, int NB)
{
    __shared__ int cnt[WNODES];
    __shared__ int lcur[WNODES];
    __shared__ int sA[MAXNB], sB[MAXNB];
    __shared__ int stg[STG_CAP];
    int b   = blockIdx.x;
    int tid = threadIdx.x;

    // local scan of bcnt -> gb0/gb1
    for (int i = tid; i < MAXNB; i += 256) sA[i] = (i < NB) ? bcnt[i] : 0;
    __syncthreads();
    int* sp = sA; int* dp = sB;
    for (int off = 1; off < MAXNB; off <<= 1) {
        for (int i = tid; i < MAXNB; i += 256)
            dp[i] = sp[i] + ((i >= off) ? sp[i - off] : 0);
        __syncthreads();
        int* t = sp; sp = dp; dp = t;
    }
    int gb1 = sp[b];
    int gb0 = gb1 - bcnt[b];
    int m   = gb1 - gb0;
    int nb0 = b << WBITS;

    if (tid < WNODES) cnt[tid] = 0;
    __syncthreads();
    for (int i = tid; i < m; i += 256)
        atomicAdd(&cnt[B1[gb0 + i] >> 17], 1);
    __syncthreads();
    // scan of per-node counts (256 wide, 256 threads)
    int v0 = (tid < WNODES) ? cnt[tid] : 0;
    sA[tid] = v0;
    __syncthreads();
    sp = sA; dp = sB;
    for (int off = 1; off < WNODES; off <<= 1) {
        dp[tid] = sp[tid] + ((tid >= off) ? sp[tid - off] : 0);
        __syncthreads();
        int* t = sp; sp = dp; dp = t;
    }
    if (tid < WNODES) {
        int ex = sp[tid] - v0;
        lcur[tid] = ex;
        int node = nb0 + tid;
        if (node < N) row_ptr[node] = gb0 + ex;
    }
    __syncthreads();
    if (m <= STG_CAP) {
        for (int i = tid; i < m; i += 256) {
            int v = B1[gb0 + i];
            int p = atomicAdd(&lcur[v >> 17], 1);
            stg[p] = v & 0x1FFFF;
        }
        __syncthreads();
        for (int i = tid; i < m; i += 256)
            col[gb0 + i] = stg[i];
    } else {               // adversarial-degree fallback (correct, uncoalesced)
        for (int i = tid; i < m; i += 256) {
            int v = B1[gb0 + i];
            int p = atomicAdd(&lcur[v >> 17], 1);
            col[gb0 + p] = v & 0x1FFFF;
        }
    }
}

// ---------------- fused gather (+ next-layer GEMM | head) ----------------
// Wave = 4 nodes/pass x 4 passes = 16 nodes; quarter q owns a node, lane t
// holds comps [4t,4t+4) as uint2. Edges clamp-padded to multiple of 8 (dup of
// last neighbor; cache-hot). ds_swizzle broadcasts col indices (MLP 8).
// Subtraction uses the node's own fp16 row (no f32 mirror).
// HEAD=false: agg -> LDS tile -> per-wave 16-row MFMA -> y16o.
// HEAD=true:  agg . v + b -> sigmoid -> out.
template<bool HEAD>
__global__ __launch_bounds__(256) void gather_fused_k(
    const int* __restrict__ rp, const int* __restrict__ col,
    const uint2* __restrict__ y16,
    const __fp16* __restrict__ W,
    unsigned short* __restrict__ y16o,
    const float* __restrict__ vv, const float* __restrict__ bptr,
    float* __restrict__ out, int n)
{
    __shared__ __fp16 sAgg[4][16][80];   // 160B row stride: 16B-aligned b128 reads
    int lane = threadIdx.x & 63;
    int wid  = threadIdx.x >> 6;
    int q = lane >> 4, t = lane & 15;
    int base = blockIdx.x * 64 + wid * 16;

    for (int p = 0; p < 4; ++p) {
        int node  = base + p * 4 + q;
        bool alive = node < n;
        int beg = 0, cnt = 0;
        if (alive) { beg = rp[node]; cnt = rp[node + 1] - beg; }
        unsigned c0 = PKNINF, c1 = PKNINF;
        if (cnt > 0) {
            int pcnt = (cnt + 7) & ~7;
            int e = 0;
            while (e < pcnt) {
                int myc = col[beg + min(e + t, cnt - 1)];
                G8(0);
                if (e + 8 < pcnt) { G8(8); }
                e += 16;
            }
        }
        if (alive) {
            bool has = cnt > 0;
            uint2 yi2 = y16[(size_t)node * 16 + t];
            float g0 = has ? (h2lo(c0) - h2lo(yi2.x)) : 0.f;
            float g1 = has ? (h2hi(c0) - h2hi(yi2.x)) : 0.f;
            float g2 = has ? (h2lo(c1) - h2lo(yi2.y)) : 0.f;
            float g3 = has ? (h2hi(c1) - h2hi(yi2.y)) : 0.f;
            if (!HEAD) {
                uint2 pk; pk.x = pkrtz(g0, g1); pk.y = pkrtz(g2, g3);
                *(uint2*)&sAgg[wid][p * 4 + q][4 * t] = pk;
            } else {
                float4 vp = ((const float4*)vv)[t];
                float s = g0 * vp.x + g1 * vp.y + g2 * vp.z + g3 * vp.w;
                s += __shfl_xor(s, 8);
                s += __shfl_xor(s, 4);
                s += __shfl_xor(s, 2);
                s += __shfl_xor(s, 1);
                if (t == 0)
                    out[node] = 1.f / (1.f + __expf(-(s + bptr[0])));
            }
        } else if (!HEAD) {
            uint2 z; z.x = 0u; z.y = 0u;
            *(uint2*)&sAgg[wid][p * 4 + q][4 * t] = z;
        }
    }

    if (!HEAD) {
        __syncthreads();
        f16x8 af[4][2];
        #pragma unroll
        for (int dt = 0; dt < 4; ++dt)
            #pragma unroll
            for (int kf = 0; kf < 2; ++kf)
                af[dt][kf] = *(const f16x8*)(W + (size_t)(dt * 16 + t) * 64 + q * 8 + kf * 32);
        f16x8 bf[2];
        #pragma unroll
        for (int kf = 0; kf < 2; ++kf)
            bf[kf] = *(const f16x8*)&sAgg[wid][t][q * 8 + kf * 32];

        int r = base + t;
        int d4 = q * 4;
        #pragma unroll
        for (int dt = 0; dt < 4; ++dt) {
            f32x4 acc = {0.f, 0.f, 0.f, 0.f};
            acc = __builtin_amdgcn_mfma_f32_16x16x32_f16(af[dt][0], bf[0], acc, 0, 0, 0);
            acc = __builtin_amdgcn_mfma_f32_16x16x32_f16(af[dt][1], bf[1], acc, 0, 0, 0);
            if (r < n) {
                uint2 pk; pk.x = pkrtz(acc[0], acc[1]); pk.y = pkrtz(acc[2], acc[3]);
                *(uint2*)(y16o + (size_t)r * 64 + dt * 16 + d4) = pk;
            }
        }
    }
}

extern "C" void kernel_launch(void* const* d_in, const int* in_sizes, int n_in,
                              void* d_out, int out_size, void* d_ws, size_t ws_size,
                              hipStream_t stream)
{
    const float* x     = (const float*)d_in[0];
    const int*   edges = (const int*)d_in[1];   // int32 view, [2][E]
    const float* Wp    = (const float*)d_in[2];
    const float* Wt    = (const float*)d_in[3];
    const float* Wout  = (const float*)d_in[4];
    const float* bout  = (const float*)d_in[5];
    const int N = in_sizes[0] / 64;             // 100000
    const int E = in_sizes[1] / 2;              // 1600000
    const int NB = (N + WNODES - 1) >> WBITS;   // 391
    float* out = (float*)d_out;

    char* ws = (char*)d_ws;
    unsigned short* y16A = (unsigned short*)ws; ws += (size_t)N * 64 * 2;
    unsigned short* y16B = (unsigned short*)ws; ws += (size_t)N * 64 * 2;
    int*   B1  = (int*)y16B;                    // alias: B1 dead before y16B live
    int* col     = (int*)ws; ws += (size_t)(E + 8) * 4;
    int* row_ptr = (int*)ws; ws += (size_t)(N + 4) * 4;
    int* bcnt    = (int*)ws; ws += MAXNB * 4;
    int* gcur    = (int*)ws; ws += MAXNB * 4;
    __fp16* Wh = (__fp16*)ws; ws += 3 * 4096 * 2;
    float*  vv = (float*)ws;  ws += 64 * 4;

    const int chunkBlocks = (E + CHUNK - 1) / CHUNK;           // 391
    const int gemmBlocks  = ((N + 15) / 16 + 3) / 4;           // 1563
    const int fusedBlocks = (N + 63) / 64;                     // 1563

    prep_k<<<3, 256, 0, stream>>>(Wp, Wt, Wout, Wh, vv, bcnt, gcur, row_ptr, N, E);

    // hist (blocks<chunkBlocks) + layer-1 GEMM (rest), overlapped
    hist_gemm_k<<<chunkBlocks + gemmBlocks, 256, 0, stream>>>(
        edges, bcnt, E, NB, chunkBlocks, x, Wh, y16A, N);
    partA_k<<<chunkBlocks, 256, 0, stream>>>(edges, bcnt, gcur, B1, E, NB);
    partB_k<<<NB, 256, 0, stream>>>(B1, bcnt, row_ptr, col, N, NB);

    // gather L1 + GEMM L2 -> y16B
    gather_fused_k<false><<<fusedBlocks, 256, 0, stream>>>(
        row_ptr, col, (const uint2*)y16A, Wh + 4096, y16B,
        nullptr, nullptr, nullptr, N);
    // gather L2 + GEMM L3 -> y16A
    gather_fused_k<false><<<fusedBlocks, 256, 0, stream>>>(
        row_ptr, col, (const uint2*)y16B, Wh + 8192, y16A,
        nullptr, nullptr, nullptr, N);
    // gather L3 + head -> out
    gather_fused_k<true><<<fusedBlocks, 256, 0, stream>>>(
        row_ptr, col, (const uint2*)y16A, nullptr, nullptr,
        vv, bout, out, N);
}

// Round 12
// 179.343 us; speedup vs baseline: 1.0247x; 1.0247x over previous
//
#include <hip/hip_runtime.h>
#include <math.h>

// ---------------------------------------------------------------------------
// PointSampler / DevConv: CSR-gather (4 nodes/wave, clamp-padded, swizzle
// broadcast) fused with the next layer's MFMA fp16 GEMM. fp16-only state.
//   memset(bcnt,gcur) -> [prep ∥ hist] -> [partA ∥ gemm1] -> partB
//   fused l: gather(y16) -> LDS agg tile -> MFMA -> y16other
//   final:   gather + Linear(D,1)+sigmoid head
// Gather is at the ~2 TB/s random-line L2-miss service floor (r8 vs r10:
// identical GB/ms at wildly different VALU/occupancy) — don't touch it.
// ---------------------------------------------------------------------------

#define WBITS 8
#define WNODES 256            // nodes per bucket
#define MAXNB 512             // max buckets (N <= 131072, src < 2^17)
#define CHUNK 4096            // edges per partA/hist block
#define STG_CAP 12288         // partB LDS staging entries (48 KB)

#define PKNINF 0xFC00FC00u    // packed fp16 (-inf, -inf)

typedef __fp16 h2v __attribute__((ext_vector_type(2)));
typedef _Float16 f16x8 __attribute__((ext_vector_type(8)));
typedef float f32x4 __attribute__((ext_vector_type(4)));

__device__ __forceinline__ unsigned pkmax(unsigned a, unsigned b) {
    unsigned r;
    asm("v_pk_max_f16 %0, %1, %2" : "=v"(r) : "v"(a), "v"(b));
    return r;
}
__device__ __forceinline__ unsigned pkrtz(float a, float b) {
    h2v r = __builtin_amdgcn_cvt_pkrtz(a, b);
    return *reinterpret_cast<unsigned*>(&r);
}
__device__ __forceinline__ float h2lo(unsigned u) {
    h2v h = *reinterpret_cast<h2v*>(&u);
    return (float)h.x;
}
__device__ __forceinline__ float h2hi(unsigned u) {
    h2v h = *reinterpret_cast<h2v*>(&u);
    return (float)h.y;
}

// 8 edges: broadcast col idx from quarter-lane K0+k, load 8B of fp16 row, pkmax
#define G8(K0) do { \
    int j0 = __builtin_amdgcn_ds_swizzle(myc, (((K0)+0)<<5)|0x10); \
    int j1 = __builtin_amdgcn_ds_swizzle(myc, (((K0)+1)<<5)|0x10); \
    int j2 = __builtin_amdgcn_ds_swizzle(myc, (((K0)+2)<<5)|0x10); \
    int j3 = __builtin_amdgcn_ds_swizzle(myc, (((K0)+3)<<5)|0x10); \
    int j4 = __builtin_amdgcn_ds_swizzle(myc, (((K0)+4)<<5)|0x10); \
    int j5 = __builtin_amdgcn_ds_swizzle(myc, (((K0)+5)<<5)|0x10); \
    int j6 = __builtin_amdgcn_ds_swizzle(myc, (((K0)+6)<<5)|0x10); \
    int j7 = __builtin_amdgcn_ds_swizzle(myc, (((K0)+7)<<5)|0x10); \
    uint2 w0 = y16[(size_t)j0 * 16 + t]; \
    uint2 w1 = y16[(size_t)j1 * 16 + t]; \
    uint2 w2 = y16[(size_t)j2 * 16 + t]; \
    uint2 w3 = y16[(size_t)j3 * 16 + t]; \
    uint2 w4 = y16[(size_t)j4 * 16 + t]; \
    uint2 w5 = y16[(size_t)j5 * 16 + t]; \
    uint2 w6 = y16[(size_t)j6 * 16 + t]; \
    uint2 w7 = y16[(size_t)j7 * 16 + t]; \
    c0 = pkmax(c0, pkmax(pkmax(pkmax(w0.x, w1.x), pkmax(w2.x, w3.x)), \
                         pkmax(pkmax(w4.x, w5.x), pkmax(w6.x, w7.x)))); \
    c1 = pkmax(c1, pkmax(pkmax(pkmax(w0.y, w1.y), pkmax(w2.y, w3.y)), \
                         pkmax(pkmax(w4.y, w5.y), pkmax(w6.y, w7.y)))); \
} while (0)

// blocks 0-2: weight prep (Wh1=fp16(Wp1@Wt0), Wh2=fp16(Wp2@Wt1), Wh0, vv,
//             row_ptr[N]=E). blocks 3..: per-chunk dst-bucket histogram.
__global__ __launch_bounds__(256) void prep_hist_k(
    const float* __restrict__ Wp, const float* __restrict__ Wt,
    const float* __restrict__ Wout,
    __fp16* __restrict__ Wh, float* __restrict__ vout,
    int* __restrict__ row_ptr, int N, int E,
    const int* __restrict__ eidx, int* __restrict__ bcnt, int NB)
{
    __shared__ float A[4096];
    __shared__ float B[4096];
    __shared__ int h[MAXNB];
    int tid = threadIdx.x;
    int b = blockIdx.x;
    if (b >= 3) {            // ---- histogram chunk ----
        for (int i = tid; i < MAXNB; i += 256) h[i] = 0;
        __syncthreads();
        int start = (b - 3) * CHUNK;
        int end = min(E, start + CHUNK);
        for (int e = start + tid; e < end; e += 256)
            atomicAdd(&h[eidx[E + e] >> WBITS], 1);
        __syncthreads();
        for (int i = tid; i < NB; i += 256)
            if (h[i]) atomicAdd(&bcnt[i], h[i]);
        return;
    }
    if (b < 2) {
        if (b == 1 && tid == 0) row_ptr[N] = E;
        const float* Ap = Wp + (size_t)(b + 1) * 4096;
        const float* Bp = Wt + (size_t)b * 4096;
        for (int i = tid; i < 4096; i += 256) { A[i] = Ap[i]; B[i] = Bp[i]; }
        __syncthreads();
        __fp16* C = Wh + (size_t)(b + 1) * 4096;
        for (int i = tid; i < 4096; i += 256) {
            int d = i >> 6, k = i & 63;
            float s = 0.f;
            #pragma unroll
            for (int m = 0; m < 64; ++m) s += A[d * 64 + m] * B[m * 64 + k];
            C[i] = (__fp16)s;
        }
    } else {
        for (int i = tid; i < 4096; i += 256) {
            A[i] = Wt[2 * 4096 + i];
            Wh[i] = (__fp16)Wp[i];
        }
        if (tid < 64) B[tid] = Wout[tid];
        __syncthreads();
        if (tid < 64) {
            float s = 0.f;
            #pragma unroll
            for (int m = 0; m < 64; ++m) s += B[m] * A[m * 64 + tid];
            vout[tid] = s;
        }
    }
}

// blocks [0, chunkBlocks): partition edges into bucket-major order (packed
// src | dstLow<<17); local scan of bcnt gives bases, gcur is zero-based.
// blocks [chunkBlocks, ...): layer-1 MFMA GEMM  y16 = fp16(x @ Wh0.T).
__global__ __launch_bounds__(256) void partA_gemm_k(
    const int* __restrict__ eidx, const int* __restrict__ bcnt,
    int* __restrict__ gcur, int* __restrict__ B1, int E, int NB,
    int chunkBlocks,
    const float* __restrict__ xin, const __fp16* __restrict__ W,
    unsigned short* __restrict__ y16o, int n)
{
    __shared__ int hist[MAXNB];
    __shared__ int lofs[MAXNB];
    __shared__ int lcur[MAXNB];
    __shared__ int gofs[MAXNB];
    __shared__ int sA[MAXNB], sB[MAXNB];
    __shared__ int stg_val[CHUNK];
    __shared__ int stg_pos[CHUNK];
    int tid = threadIdx.x;
    if (blockIdx.x >= chunkBlocks) {   // ---- layer-1 GEMM ----
        int lane = tid & 63;
        int wid  = tid >> 6;
        int r0   = ((blockIdx.x - chunkBlocks) * 4 + wid) * 16;
        if (r0 >= n) return;
        int l15 = lane & 15;
        int ko  = (lane >> 4) * 8;

        f16x8 af[4][2];
        #pragma unroll
        for (int dt = 0; dt < 4; ++dt)
            #pragma unroll
            for (int kf = 0; kf < 2; ++kf)
                af[dt][kf] = *(const f16x8*)(W + (size_t)(dt * 16 + l15) * 64 + ko + kf * 32);

        f16x8 bf[2];
        int rr = min(r0 + l15, n - 1);
        #pragma unroll
        for (int kf = 0; kf < 2; ++kf) {
            const float4* p = (const float4*)(xin + (size_t)rr * 64 + ko + kf * 32);
            float4 a = p[0], b = p[1];
            union { uint4 u; f16x8 hh; } cv;
            cv.u.x = pkrtz(a.x, a.y); cv.u.y = pkrtz(a.z, a.w);
            cv.u.z = pkrtz(b.x, b.y); cv.u.w = pkrtz(b.z, b.w);
            bf[kf] = cv.hh;
        }

        int r = r0 + l15;
        int d4 = (lane >> 4) * 4;
        #pragma unroll
        for (int dt = 0; dt < 4; ++dt) {
            f32x4 acc = {0.f, 0.f, 0.f, 0.f};
            acc = __builtin_amdgcn_mfma_f32_16x16x32_f16(af[dt][0], bf[0], acc, 0, 0, 0);
            acc = __builtin_amdgcn_mfma_f32_16x16x32_f16(af[dt][1], bf[1], acc, 0, 0, 0);
            if (r < n) {
                uint2 p; p.x = pkrtz(acc[0], acc[1]); p.y = pkrtz(acc[2], acc[3]);
                *(uint2*)(y16o + (size_t)r * 64 + dt * 16 + d4) = p;
            }
        }
        return;
    }

    // ---- partA ----
    int start = blockIdx.x * CHUNK;
    int cnt = min(E - start, CHUNK);
    if (cnt <= 0) return;

    for (int i = tid; i < MAXNB; i += 256) hist[i] = 0;
    __syncthreads();

    int es[CHUNK / 256], ed[CHUNK / 256];
    #pragma unroll
    for (int i = 0; i < CHUNK / 256; ++i) {
        int li = i * 256 + tid;
        if (li < cnt) {
            es[i] = eidx[start + li];
            ed[i] = eidx[E + start + li];
            atomicAdd(&hist[ed[i] >> WBITS], 1);
        }
    }
    __syncthreads();
    // scan 1: global bcnt -> exclusive bases (redundant per block, cheap)
    for (int i = tid; i < MAXNB; i += 256) sA[i] = (i < NB) ? bcnt[i] : 0;
    __syncthreads();
    int* sp = sA; int* dp = sB;
    for (int off = 1; off < MAXNB; off <<= 1) {
        for (int i = tid; i < MAXNB; i += 256)
            dp[i] = sp[i] + ((i >= off) ? sp[i - off] : 0);
        __syncthreads();
        int* t = sp; sp = dp; dp = t;
    }
    for (int i = tid; i < MAXNB; i += 256)
        gofs[i] = sp[i] - ((i < NB) ? bcnt[i] : 0);   // exclusive global base
    __syncthreads();
    // scan 2: local chunk hist -> local staging offsets
    for (int i = tid; i < MAXNB; i += 256) sp[i] = hist[i];
    __syncthreads();
    for (int off = 1; off < MAXNB; off <<= 1) {
        for (int i = tid; i < MAXNB; i += 256)
            dp[i] = sp[i] + ((i >= off) ? sp[i - off] : 0);
        __syncthreads();
        int* t = sp; sp = dp; dp = t;
    }
    for (int i = tid; i < MAXNB; i += 256) {
        int c  = hist[i];
        int ex = sp[i] - c;
        lofs[i] = ex;
        lcur[i] = ex;
        if (c) gofs[i] += atomicAdd(&gcur[i], c);
    }
    __syncthreads();
    #pragma unroll
    for (int i = 0; i < CHUNK / 256; ++i) {
        int li = i * 256 + tid;
        if (li < cnt) {
            int b = ed[i] >> WBITS;
            int p = atomicAdd(&lcur[b], 1);
            stg_val[p] = es[i] | ((ed[i] & (WNODES - 1)) << 17);
            stg_pos[p] = gofs[b] + (p - lofs[b]);
        }
    }
    __syncthreads();
    for (int i = tid; i < cnt; i += 256)
        B1[stg_pos[i]] = stg_val[i];
}

// per-bucket: degree count -> scan -> row_ptr; LDS-staged coalesced col scatter.
// Bucket bases re-derived by a local scan of bcnt.
__global__ __launch_bounds__(256) void partB_k(
    const int* __restrict__ B1, const int* __restrict__ bcnt,
    int* __restrict__ row_ptr, int* __restrict__ col, int N, int NB)
{
    __shared__ int cnt[WNODES];
    __shared__ int lcur[WNODES];
    __shared__ int sA[MAXNB], sB[MAXNB];
    __shared__ int stg[STG_CAP];
    int b   = blockIdx.x;
    int tid = threadIdx.x;

    // local scan of bcnt -> gb0/gb1
    for (int i = tid; i < MAXNB; i += 256) sA[i] = (i < NB) ? bcnt[i] : 0;
    __syncthreads();
    int* sp = sA; int* dp = sB;
    for (int off = 1; off < MAXNB; off <<= 1) {
        for (int i = tid; i < MAXNB; i += 256)
            dp[i] = sp[i] + ((i >= off) ? sp[i - off] : 0);
        __syncthreads();
        int* t = sp; sp = dp; dp = t;
    }
    int gb1 = sp[b];
    int gb0 = gb1 - bcnt[b];
    int m   = gb1 - gb0;
    int nb0 = b << WBITS;

    if (tid < WNODES) cnt[tid] = 0;
    __syncthreads();
    for (int i = tid; i < m; i += 256)
        atomicAdd(&cnt[B1[gb0 + i] >> 17], 1);
    __syncthreads();
    // scan of per-node counts (256 wide, 256 threads)
    int v0 = (tid < WNODES) ? cnt[tid] : 0;
    sA[tid] = v0;
    __syncthreads();
    sp = sA; dp = sB;
    for (int off = 1; off < WNODES; off <<= 1) {
        dp[tid] = sp[tid] + ((tid >= off) ? sp[tid - off] : 0);
        __syncthreads();
        int* t = sp; sp = dp; dp = t;
    }
    if (tid < WNODES) {
        int ex = sp[tid] - v0;
        lcur[tid] = ex;
        int node = nb0 + tid;
        if (node < N) row_ptr[node] = gb0 + ex;
    }
    __syncthreads();
    if (m <= STG_CAP) {
        for (int i = tid; i < m; i += 256) {
            int v = B1[gb0 + i];
            int p = atomicAdd(&lcur[v >> 17], 1);
            stg[p] = v & 0x1FFFF;
        }
        __syncthreads();
        for (int i = tid; i < m; i += 256)
            col[gb0 + i] = stg[i];
    } else {               // adversarial-degree fallback (correct, uncoalesced)
        for (int i = tid; i < m; i += 256) {
            int v = B1[gb0 + i];
            int p = atomicAdd(&lcur[v >> 17], 1);
            col[gb0 + p] = v & 0x1FFFF;
        }
    }
}

// ---------------- fused gather (+ next-layer GEMM | head) ----------------
// Wave = 4 nodes/pass x 4 passes = 16 nodes; quarter q owns a node, lane t
// holds comps [4t,4t+4) as uint2. Edges clamp-padded to multiple of 8 (dup of
// last neighbor; cache-hot). ds_swizzle broadcasts col indices (MLP 8).
// Subtraction uses the node's own fp16 row (no f32 mirror).
// HEAD=false: agg -> LDS tile -> per-wave 16-row MFMA -> y16o.
// HEAD=true:  agg . v + b -> sigmoid -> out.
template<bool HEAD>
__global__ __launch_bounds__(256) void gather_fused_k(
    const int* __restrict__ rp, const int* __restrict__ col,
    const uint2* __restrict__ y16,
    const __fp16* __restrict__ W,
    unsigned short* __restrict__ y16o,
    const float* __restrict__ vv, const float* __restrict__ bptr,
    float* __restrict__ out, int n)
{
    __shared__ __fp16 sAgg[4][16][80];   // 160B row stride: 16B-aligned b128 reads
    int lane = threadIdx.x & 63;
    int wid  = threadIdx.x >> 6;
    int q = lane >> 4, t = lane & 15;
    int base = blockIdx.x * 64 + wid * 16;

    for (int p = 0; p < 4; ++p) {
        int node  = base + p * 4 + q;
        bool alive = node < n;
        int beg = 0, cnt = 0;
        if (alive) { beg = rp[node]; cnt = rp[node + 1] - beg; }
        unsigned c0 = PKNINF, c1 = PKNINF;
        if (cnt > 0) {
            int pcnt = (cnt + 7) & ~7;
            int e = 0;
            while (e < pcnt) {
                int myc = col[beg + min(e + t, cnt - 1)];
                G8(0);
                if (e + 8 < pcnt) { G8(8); }
                e += 16;
            }
        }
        if (alive) {
            bool has = cnt > 0;
            uint2 yi2 = y16[(size_t)node * 16 + t];
            float g0 = has ? (h2lo(c0) - h2lo(yi2.x)) : 0.f;
            float g1 = has ? (h2hi(c0) - h2hi(yi2.x)) : 0.f;
            float g2 = has ? (h2lo(c1) - h2lo(yi2.y)) : 0.f;
            float g3 = has ? (h2hi(c1) - h2hi(yi2.y)) : 0.f;
            if (!HEAD) {
                uint2 pk; pk.x = pkrtz(g0, g1); pk.y = pkrtz(g2, g3);
                *(uint2*)&sAgg[wid][p * 4 + q][4 * t] = pk;
            } else {
                float4 vp = ((const float4*)vv)[t];
                float s = g0 * vp.x + g1 * vp.y + g2 * vp.z + g3 * vp.w;
                s += __shfl_xor(s, 8);
                s += __shfl_xor(s, 4);
                s += __shfl_xor(s, 2);
                s += __shfl_xor(s, 1);
                if (t == 0)
                    out[node] = 1.f / (1.f + __expf(-(s + bptr[0])));
            }
        } else if (!HEAD) {
            uint2 z; z.x = 0u; z.y = 0u;
            *(uint2*)&sAgg[wid][p * 4 + q][4 * t] = z;
        }
    }

    if (!HEAD) {
        __syncthreads();
        f16x8 af[4][2];
        #pragma unroll
        for (int dt = 0; dt < 4; ++dt)
            #pragma unroll
            for (int kf = 0; kf < 2; ++kf)
                af[dt][kf] = *(const f16x8*)(W + (size_t)(dt * 16 + t) * 64 + q * 8 + kf * 32);
        f16x8 bf[2];
        #pragma unroll
        for (int kf = 0; kf < 2; ++kf)
            bf[kf] = *(const f16x8*)&sAgg[wid][t][q * 8 + kf * 32];

        int r = base + t;
        int d4 = q * 4;
        #pragma unroll
        for (int dt = 0; dt < 4; ++dt) {
            f32x4 acc = {0.f, 0.f, 0.f, 0.f};
            acc = __builtin_amdgcn_mfma_f32_16x16x32_f16(af[dt][0], bf[0], acc, 0, 0, 0);
            acc = __builtin_amdgcn_mfma_f32_16x16x32_f16(af[dt][1], bf[1], acc, 0, 0, 0);
            if (r < n) {
                uint2 pk; pk.x = pkrtz(acc[0], acc[1]); pk.y = pkrtz(acc[2], acc[3]);
                *(uint2*)(y16o + (size_t)r * 64 + dt * 16 + d4) = pk;
            }
        }
    }
}

extern "C" void kernel_launch(void* const* d_in, const int* in_sizes, int n_in,
                              void* d_out, int out_size, void* d_ws, size_t ws_size,
                              hipStream_t stream)
{
    const float* x     = (const float*)d_in[0];
    const int*   edges = (const int*)d_in[1];   // int32 view, [2][E]
    const float* Wp    = (const float*)d_in[2];
    const float* Wt    = (const float*)d_in[3];
    const float* Wout  = (const float*)d_in[4];
    const float* bout  = (const float*)d_in[5];
    const int N = in_sizes[0] / 64;             // 100000
    const int E = in_sizes[1] / 2;              // 1600000
    const int NB = (N + WNODES - 1) >> WBITS;   // 391
    float* out = (float*)d_out;

    char* ws = (char*)d_ws;
    unsigned short* y16A = (unsigned short*)ws; ws += (size_t)N * 64 * 2;
    unsigned short* y16B = (unsigned short*)ws; ws += (size_t)N * 64 * 2;
    int*   B1  = (int*)y16B;                    // alias: B1 dead before y16B live
    int* col     = (int*)ws; ws += (size_t)(E + 8) * 4;
    int* row_ptr = (int*)ws; ws += (size_t)(N + 4) * 4;
    int* bcnt    = (int*)ws; ws += MAXNB * 4;
    int* gcur    = (int*)ws; ws += MAXNB * 4;   // contiguous with bcnt (one memset)
    __fp16* Wh = (__fp16*)ws; ws += 3 * 4096 * 2;
    float*  vv = (float*)ws;  ws += 64 * 4;

    const int chunkBlocks = (E + CHUNK - 1) / CHUNK;           // 391
    const int gemmBlocks  = ((N + 15) / 16 + 3) / 4;           // 1563
    const int fusedBlocks = (N + 63) / 64;                     // 1563

    // zero bcnt+gcur (contiguous) in one async memset
    hipMemsetAsync(bcnt, 0, 2 * MAXNB * sizeof(int), stream);

    // weight prep (blocks 0-2) ∥ dst-bucket histogram (rest)
    prep_hist_k<<<3 + chunkBlocks, 256, 0, stream>>>(
        Wp, Wt, Wout, Wh, vv, row_ptr, N, E, edges, bcnt, NB);

    // partA (blocks<chunkBlocks) ∥ layer-1 GEMM (rest)
    partA_gemm_k<<<chunkBlocks + gemmBlocks, 256, 0, stream>>>(
        edges, bcnt, gcur, B1, E, NB, chunkBlocks, x, Wh, y16A, N);

    partB_k<<<NB, 256, 0, stream>>>(B1, bcnt, row_ptr, col, N, NB);

    // gather L1 + GEMM L2 -> y16B
    gather_fused_k<false><<<fusedBlocks, 256, 0, stream>>>(
        row_ptr, col, (const uint2*)y16A, Wh + 4096, y16B,
        nullptr, nullptr, nullptr, N);
    // gather L2 + GEMM L3 -> y16A
    gather_fused_k<false><<<fusedBlocks, 256, 0, stream>>>(
        row_ptr, col, (const uint2*)y16B, Wh + 8192, y16A,
        nullptr, nullptr, nullptr, N);
    // gather L3 + head -> out
    gather_fused_k<true><<<fusedBlocks, 256, 0, stream>>>(
        row_ptr, col, (const uint2*)y16A, nullptr, nullptr,
        vv, bout, out, N);
}